// Round 6
// baseline (325.902 us; speedup 1.0000x reference)
//
#include <hip/hip_runtime.h>
#include <stdint.h>

// Problem sizes (fixed): B=4, S=2048, D=1024, DQK=128, DV=256
#define SLEN 2048
#define NROWS 8192   // B*S

typedef __attribute__((ext_vector_type(4))) float f32x4;
typedef __attribute__((ext_vector_type(8))) short bf16x8;
typedef __attribute__((ext_vector_type(2))) unsigned int u32x2;
typedef __attribute__((ext_vector_type(4))) unsigned int u32x4;

__device__ __forceinline__ short f2bf(float f) {
  uint32_t u = __builtin_bit_cast(uint32_t, f);
  u += 0x7FFFu + ((u >> 16) & 1u);
  return (short)(u >> 16);
}
__device__ __forceinline__ float bf2f(short s) {
  uint32_t u = ((uint32_t)(uint16_t)s) << 16;
  return __builtin_bit_cast(float, u);
}
__device__ __forceinline__ f32x4 mfma16(bf16x8 a, bf16x8 b, f32x4 c) {
  return __builtin_amdgcn_mfma_f32_16x16x32_bf16(a, b, c, 0, 0, 0);
}
__device__ __forceinline__ void gld_lds16(const void* g, void* l) {
  __builtin_amdgcn_global_load_lds(
      (const __attribute__((address_space(1))) void*)g,
      (__attribute__((address_space(3))) void*)l, 16, 0, 0);
}

// ---------------------------------------------------------------- prep ------
// blocks [0,4096): X -> Xb (bf16)
// blocks [4096,4352): 256 LDS-tiled 64x64 weight transposes (coalesced)
// block 4352: bcat
__global__ __launch_bounds__(256) void k_prep(
    const float* __restrict__ X,
    const float* __restrict__ Wq, const float* __restrict__ bq,
    const float* __restrict__ Wk, const float* __restrict__ bk,
    const float* __restrict__ Wv, const float* __restrict__ bv,
    const float* __restrict__ Wg, const float* __restrict__ bg,
    const float* __restrict__ Wp,
    short* __restrict__ Xb, short* __restrict__ WcatT,
    short* __restrict__ WpT, float* __restrict__ bcat) {
  __shared__ short tl[64][72];
  int blk = blockIdx.x, tid = threadIdx.x;
  if (blk < 4096) {
    size_t e = ((size_t)blk * 256 + tid) * 8;
    f32x4 a = *(const f32x4*)&X[e];
    f32x4 b = *(const f32x4*)&X[e + 4];
    bf16x8 o;
    o[0] = f2bf(a[0]); o[1] = f2bf(a[1]); o[2] = f2bf(a[2]); o[3] = f2bf(a[3]);
    o[4] = f2bf(b[0]); o[5] = f2bf(b[1]); o[6] = f2bf(b[2]); o[7] = f2bf(b[3]);
    *(bf16x8*)&Xb[e] = o;
  } else if (blk < 4352) {
    int t = blk - 4096;
    const float* src; short* dst; int C, rowoff, dstC, r0, c0;
    if (t < 32)       { src = Wq; C = 128;  rowoff = 0;   dst = WcatT; dstC = 1024; r0 = (t >> 1) * 64;  c0 = (t & 1) * 64; }
    else if (t < 64)  { t -= 32;  src = Wk; C = 128;  rowoff = 128; dst = WcatT; dstC = 1024; r0 = (t >> 1) * 64;  c0 = (t & 1) * 64; }
    else if (t < 128) { t -= 64;  src = Wv; C = 256;  rowoff = 256; dst = WcatT; dstC = 1024; r0 = (t >> 2) * 64;  c0 = (t & 3) * 64; }
    else if (t < 192) { t -= 128; src = Wg; C = 256;  rowoff = 512; dst = WcatT; dstC = 1024; r0 = (t >> 2) * 64;  c0 = (t & 3) * 64; }
    else              { t -= 192; src = Wp; C = 1024; rowoff = 0;   dst = WpT;   dstC = 256;  r0 = (t >> 4) * 64;  c0 = (t & 15) * 64; }
    int lr = tid >> 4, lcc = tid & 15;
#pragma unroll
    for (int rr = 0; rr < 4; ++rr) {
      f32x4 v = *(const f32x4*)&src[(size_t)(r0 + lr * 4 + rr) * C + c0 + lcc * 4];
#pragma unroll
      for (int j = 0; j < 4; ++j) tl[lcc * 4 + j][lr * 4 + rr] = f2bf(v[j]);
    }
    __syncthreads();
    int orow = tid >> 2, og = (tid & 3) * 16;
    bf16x8 o1, o2;
#pragma unroll
    for (int j = 0; j < 8; ++j) { o1[j] = tl[orow][og + j]; o2[j] = tl[orow][og + 8 + j]; }
    size_t dbase = (size_t)(rowoff + c0 + orow) * dstC + r0 + og;
    *(bf16x8*)&dst[dbase] = o1;
    *(bf16x8*)&dst[dbase + 8] = o2;
  } else {
    int c = tid;
    if (c < 768) {
      float v;
      if (c < 128)      v = bq[c];
      else if (c < 256) v = bk[c - 128];
      else if (c < 512) v = bv[c - 256];
      else              v = bg[c - 512];
      bcat[c] = v;
    }
  }
}

// ---------------------------------------------------------------- gemm1 -----
// O[8192][768] = Xb[8192][1024] @ Wcat + bcat. Blocks with y==0/1 also emit
// q2a/k2a row norms (sum over the 128 Q/K cols of bf16-rounded values).
__global__ __launch_bounds__(256) void k_gemm1(
    const short* __restrict__ Xb, const short* __restrict__ WcatT,
    const float* __restrict__ bcat, short* __restrict__ O,
    float* __restrict__ q2a, float* __restrict__ k2a) {
  __shared__ short At[128 * 32];
  __shared__ short Bt[128 * 32];
  __shared__ float nlds[128][2];
  const int tid = threadIdx.x;
  const int w = tid >> 6, l = tid & 63, lg = l >> 4, lc = l & 15;
  const int m0 = blockIdx.x * 128, n0 = blockIdx.y * 128;
  const int sr0 = w * 32 + (l >> 2);
  const int scc = (l & 3) * 8;
  const int wm = (w >> 1) * 64, wn = (w & 1) * 64;

  f32x4 acc[4][4] = {};
  const short* Ab = Xb + (size_t)m0 * 1024;
  const short* Bb = WcatT + (size_t)n0 * 1024;

  for (int kb = 0; kb < 1024; kb += 32) {
    gld_lds16(Ab + (size_t)sr0 * 1024 + kb + scc, &At[(w * 32) * 32]);
    gld_lds16(Ab + (size_t)(sr0 + 16) * 1024 + kb + scc, &At[(w * 32 + 16) * 32]);
    gld_lds16(Bb + (size_t)sr0 * 1024 + kb + scc, &Bt[(w * 32) * 32]);
    gld_lds16(Bb + (size_t)(sr0 + 16) * 1024 + kb + scc, &Bt[(w * 32 + 16) * 32]);
    __syncthreads();
    bf16x8 af[4], bf[4];
#pragma unroll
    for (int mi = 0; mi < 4; ++mi)
      af[mi] = *(const bf16x8*)&At[(wm + mi * 16 + lc) * 32 + lg * 8];
#pragma unroll
    for (int ni = 0; ni < 4; ++ni)
      bf[ni] = *(const bf16x8*)&Bt[(wn + ni * 16 + lc) * 32 + lg * 8];
#pragma unroll
    for (int mi = 0; mi < 4; ++mi)
#pragma unroll
      for (int ni = 0; ni < 4; ++ni)
        acc[mi][ni] = mfma16(af[mi], bf[ni], acc[mi][ni]);
    __syncthreads();
  }
  float sq[4][4] = {};
#pragma unroll
  for (int mi = 0; mi < 4; ++mi) {
    int gr = m0 + wm + mi * 16 + lg * 4;
#pragma unroll
    for (int ni = 0; ni < 4; ++ni) {
      int gc = n0 + wn + ni * 16 + lc;
      float bias = bcat[gc];
#pragma unroll
      for (int r = 0; r < 4; ++r) {
        short sv = f2bf(acc[mi][ni][r] + bias);
        O[(size_t)(gr + r) * 768 + gc] = sv;
        float v = bf2f(sv);
        sq[mi][r] += v * v;
      }
    }
  }
  if (blockIdx.y < 2) {
#pragma unroll
    for (int mi = 0; mi < 4; ++mi)
#pragma unroll
      for (int r = 0; r < 4; ++r) {
        float v = sq[mi][r];
        v += __shfl_xor(v, 1, 64); v += __shfl_xor(v, 2, 64);
        v += __shfl_xor(v, 4, 64); v += __shfl_xor(v, 8, 64);
        sq[mi][r] = v;
      }
    if (lc == 0) {
#pragma unroll
      for (int mi = 0; mi < 4; ++mi)
#pragma unroll
        for (int r = 0; r < 4; ++r)
          nlds[wm + mi * 16 + lg * 4 + r][w & 1] = sq[mi][r];
    }
    __syncthreads();
    if (tid < 128) {
      float t = nlds[tid][0] + nlds[tid][1];
      (blockIdx.y == 0 ? q2a : k2a)[m0 + tid] = t;
    }
  }
}

// ---------------------------------------------------------------- vt --------
// Vtp: V transposed AND k-permuted to match the in-register P fragment:
// pos(k) = (k>>5)*32 + ((k>>2)&3)*8 + ((k>>4)&1)*4 + (k&3)
__global__ __launch_bounds__(256) void k_vt(
    const short* __restrict__ O, short* __restrict__ Vtp) {
  __shared__ short tile[64][33];
  int blk = blockIdx.x, tid = threadIdx.x;
  int b = blk >> 8, rem = blk & 255;
  int s0 = (rem >> 3) * 64, dv0 = (rem & 7) * 32;
  int r = tid >> 2, cg = (tid & 3) * 8;
  bf16x8 v = *(const bf16x8*)&O[(size_t)(b * SLEN + s0 + r) * 768 + 256 + dv0 + cg];
#pragma unroll
  for (int j = 0; j < 8; ++j) tile[r][cg + j] = v[j];
  __syncthreads();
  int dr = tid >> 3, sg = (tid & 7) * 8;
  bf16x8 ov;
#pragma unroll
  for (int j = 0; j < 8; ++j) ov[j] = tile[sg + j][dr];
  int ka = s0 + sg;
  int c5 = ka >> 5, hi = (ka >> 4) & 1, lgq = (ka >> 2) & 3;
  size_t base = (size_t)(b * 256 + dv0 + dr) * SLEN + c5 * 32 + lgq * 8 + hi * 4;
  u32x4 od = __builtin_bit_cast(u32x4, ov);
  u32x2 p0; p0[0] = od[0]; p0[1] = od[1];
  u32x2 p1; p1[0] = od[2]; p1[1] = od[3];
  *(u32x2*)&Vtp[base] = p0;        // k = ka..ka+3
  *(u32x2*)&Vtp[base + 8] = p1;    // k = ka+4..ka+7
}

// ---------------------------------------------------------------- attn ------
// Wave-independent main loop (no barriers/LDS); epilogue: h=1 waves stash
// bf16 partials (16 KB LDS), h=0 waves combine + write nump. launch_bounds
// (256,4) targets 4 blocks/CU (~50% occupancy) for latency hiding.
__global__ __launch_bounds__(256, 4) void k_attn(
    const short* __restrict__ O, const short* __restrict__ Vtp,
    const float* __restrict__ q2a, const float* __restrict__ k2a,
    short* __restrict__ nump, float* __restrict__ denp) {
  __shared__ short stash[2][16][64][4];  // [dh][combo][lane][r] bf16 = 16 KB
  __shared__ float dls[2][32];
  const int tid = threadIdx.x;
  const int w = tid >> 6, l = tid & 63, lg = l >> 4, lc = l & 15;
  const int h = w >> 1, dh = w & 1;
  const int blk = ((blockIdx.x & 7) << 7) | (blockIdx.x >> 3);  // XCD swizzle
  const int ks = blk & 3, qt = (blk >> 2) & 63, b = blk >> 8;
  const int grow0 = b * SLEN + qt * 32;
  const int kloc0 = ks * 512 + h * 256;       // within-batch k base for wave
  const int krow0 = b * SLEN + kloc0;         // global row base into O/k2a

  bf16x8 qf[2][4];
#pragma unroll
  for (int mi = 0; mi < 2; ++mi)
#pragma unroll
    for (int kf = 0; kf < 4; ++kf)
      qf[mi][kf] = *(const bf16x8*)&O[(size_t)(grow0 + mi * 16 + lc) * 768 + kf * 32 + lg * 8];

  float q2s[2];
  q2s[0] = q2a[grow0 + lc];
  q2s[1] = q2a[grow0 + 16 + lc];

  f32x4 acc[2][8] = {};
  float den0 = 0.f, den1 = 0.f;
  const short* vbase = Vtp + (size_t)(b * 256 + dh * 128 + lc) * SLEN;

#pragma unroll 2
  for (int c = 0; c < 8; ++c) {
    const int kr = krow0 + c * 32;
    f32x4 s[2][2] = {};
#pragma unroll
    for (int e = 0; e < 2; ++e)
#pragma unroll
      for (int kf = 0; kf < 4; ++kf) {
        bf16x8 kv = *(const bf16x8*)&O[(size_t)(kr + e * 16 + lc) * 768 + 128 + kf * 32 + lg * 8];
        s[0][e] = mfma16(kv, qf[0][kf], s[0][e]);
        s[1][e] = mfma16(kv, qf[1][kf], s[1][e]);
      }
    float wv[2][2][4];
#pragma unroll
    for (int e = 0; e < 2; ++e) {
      f32x4 k2v = *(const f32x4*)&k2a[kr + e * 16 + lg * 4];
#pragma unroll
      for (int mi = 0; mi < 2; ++mi)
#pragma unroll
        for (int r = 0; r < 4; ++r) {
          float d2 = q2s[mi] + k2v[r] - 2.0f * s[mi][e][r];
          wv[mi][e][r] = __builtin_amdgcn_rcpf(fmaxf(d2, 1e-16f));
        }
    }
#pragma unroll
    for (int r = 0; r < 4; ++r) {
      den0 += wv[0][0][r] + wv[0][1][r];
      den1 += wv[1][0][r] + wv[1][1][r];
    }
    bf16x8 pa[2];
#pragma unroll
    for (int mi = 0; mi < 2; ++mi) {
#pragma unroll
      for (int r = 0; r < 4; ++r) {
        pa[mi][r] = f2bf(wv[mi][0][r]);      // slots 0-3: k = lg*4+r
        pa[mi][4 + r] = f2bf(wv[mi][1][r]);  // slots 4-7: k = 16+lg*4+r
      }
    }
    const int voff = kloc0 + c * 32 + lg * 8;
#pragma unroll
    for (int nv = 0; nv < 8; ++nv) {
      bf16x8 bv = *(const bf16x8*)&vbase[(size_t)nv * 16 * SLEN + voff];
      acc[0][nv] = mfma16(pa[0], bv, acc[0][nv]);
      acc[1][nv] = mfma16(pa[1], bv, acc[1][nv]);
    }
  }
  // den: reduce over lg groups within wave; dh==0 waves publish per-k-half
  den0 += __shfl_xor(den0, 16, 64); den0 += __shfl_xor(den0, 32, 64);
  den1 += __shfl_xor(den1, 16, 64); den1 += __shfl_xor(den1, 32, 64);
  if (dh == 0 && l < 16) { dls[h][l] = den0; dls[h][16 + l] = den1; }
  // h==1 waves stash bf16 partials
  if (h == 1) {
#pragma unroll
    for (int mi = 0; mi < 2; ++mi)
#pragma unroll
      for (int nv = 0; nv < 8; ++nv) {
        f32x4 a = acc[mi][nv];
        u32x2 pk;
        pk[0] = (uint32_t)(uint16_t)f2bf(a[0]) | ((uint32_t)(uint16_t)f2bf(a[1]) << 16);
        pk[1] = (uint32_t)(uint16_t)f2bf(a[2]) | ((uint32_t)(uint16_t)f2bf(a[3]) << 16);
        *(u32x2*)&stash[dh][mi * 8 + nv][l][0] = pk;
      }
  }
  __syncthreads();
  if (h == 0) {
    const size_t pbase = (size_t)blk * 32 * 256;
#pragma unroll
    for (int mi = 0; mi < 2; ++mi)
#pragma unroll
      for (int nv = 0; nv < 8; ++nv) {
        u32x2 sv = *(const u32x2*)&stash[dh][mi * 8 + nv][l][0];
        f32x4 a = acc[mi][nv];
        a[0] += bf2f((short)(sv[0] & 0xFFFFu));
        a[1] += bf2f((short)(sv[0] >> 16));
        a[2] += bf2f((short)(sv[1] & 0xFFFFu));
        a[3] += bf2f((short)(sv[1] >> 16));
        int dv = dh * 128 + nv * 16 + lc;
        int rb = mi * 16 + lg * 4;
#pragma unroll
        for (int r = 0; r < 4; ++r)
          nump[pbase + (size_t)(rb + r) * 256 + dv] = f2bf(a[r]);
      }
  }
  if (tid < 32) denp[blk * 32 + tid] = dls[0][tid] + dls[1][tid];
}

// ---------------------------------------------------------------- red -------
// AG[row][dv] = (sum_ks nump) / (sum_ks denp) * G[row][dv]
__global__ __launch_bounds__(256) void k_red(
    const short* __restrict__ nump, const float* __restrict__ denp,
    const short* __restrict__ O, short* __restrict__ AG) {
  int flat = blockIdx.x * 256 + threadIdx.x;   // 0..262143
  int idx8 = flat * 8;
  int row = idx8 >> 8;
  int dv0 = idx8 & 255;
  int b = row >> 11, srow = row & 2047;
  int qt = srow >> 5, rit = srow & 31;
  int blkbase = (b * 64 + qt) << 2;
  float num[8] = {};
  float den = 0.f;
#pragma unroll
  for (int ksi = 0; ksi < 4; ++ksi) {
    const size_t base = ((size_t)(blkbase + ksi) * 32 + rit) * 256 + dv0;
    bf16x8 v = *(const bf16x8*)&nump[base];
#pragma unroll
    for (int j = 0; j < 8; ++j) num[j] += bf2f(v[j]);
    den += denp[(blkbase + ksi) * 32 + rit];
  }
  float rden = 1.f / den;
  bf16x8 gv = *(const bf16x8*)&O[(size_t)row * 768 + 512 + dv0];
  bf16x8 o;
#pragma unroll
  for (int j = 0; j < 8; ++j) o[j] = f2bf(num[j] * rden * bf2f(gv[j]));
  *(bf16x8*)&AG[idx8] = o;
}

// ---------------------------------------------------------------- gemm3 -----
// Y[8192][1024] = X + AG[8192][256] @ Wp + bp
__global__ __launch_bounds__(256) void k_gemm3(
    const short* __restrict__ AG, const short* __restrict__ WpT,
    const float* __restrict__ X, const float* __restrict__ bp,
    float* __restrict__ Y) {
  __shared__ short At[128 * 32];
  __shared__ short Bt[128 * 32];
  const int tid = threadIdx.x;
  const int w = tid >> 6, l = tid & 63, lg = l >> 4, lc = l & 15;
  const int m0 = blockIdx.x * 128, n0 = blockIdx.y * 128;
  const int sr0 = w * 32 + (l >> 2);
  const int scc = (l & 3) * 8;
  const int wm = (w >> 1) * 64, wn = (w & 1) * 64;

  f32x4 acc[4][4] = {};
  const short* Ab = AG + (size_t)m0 * 256;
  const short* Bb = WpT + (size_t)n0 * 256;

  for (int kb = 0; kb < 256; kb += 32) {
    gld_lds16(Ab + (size_t)sr0 * 256 + kb + scc, &At[(w * 32) * 32]);
    gld_lds16(Ab + (size_t)(sr0 + 16) * 256 + kb + scc, &At[(w * 32 + 16) * 32]);
    gld_lds16(Bb + (size_t)sr0 * 256 + kb + scc, &Bt[(w * 32) * 32]);
    gld_lds16(Bb + (size_t)(sr0 + 16) * 256 + kb + scc, &Bt[(w * 32 + 16) * 32]);
    __syncthreads();
    bf16x8 af[4], bf[4];
#pragma unroll
    for (int mi = 0; mi < 4; ++mi)
      af[mi] = *(const bf16x8*)&At[(wm + mi * 16 + lc) * 32 + lg * 8];
#pragma unroll
    for (int ni = 0; ni < 4; ++ni)
      bf[ni] = *(const bf16x8*)&Bt[(wn + ni * 16 + lc) * 32 + lg * 8];
#pragma unroll
    for (int mi = 0; mi < 4; ++mi)
#pragma unroll
      for (int ni = 0; ni < 4; ++ni)
        acc[mi][ni] = mfma16(af[mi], bf[ni], acc[mi][ni]);
    __syncthreads();
  }
#pragma unroll
  for (int mi = 0; mi < 4; ++mi) {
    int gr = m0 + wm + mi * 16 + lg * 4;
#pragma unroll
    for (int ni = 0; ni < 4; ++ni) {
      int gc = n0 + wn + ni * 16 + lc;
      float bias = bp[gc];
#pragma unroll
      for (int r = 0; r < 4; ++r) {
        size_t idx = (size_t)(gr + r) * 1024 + gc;
        Y[idx] = acc[mi][ni][r] + X[idx] + bias;
      }
    }
  }
}

// ---------------------------------------------------------------- launch ----
extern "C" void kernel_launch(void* const* d_in, const int* in_sizes, int n_in,
                              void* d_out, int out_size, void* d_ws, size_t ws_size,
                              hipStream_t stream) {
  const float* X  = (const float*)d_in[0];
  const float* Wq = (const float*)d_in[1];
  const float* bq = (const float*)d_in[2];
  const float* Wk = (const float*)d_in[3];
  const float* bk = (const float*)d_in[4];
  const float* Wv = (const float*)d_in[5];
  const float* bv = (const float*)d_in[6];
  const float* Wg = (const float*)d_in[7];
  const float* bg = (const float*)d_in[8];
  const float* Wp = (const float*)d_in[9];
  const float* bp = (const float*)d_in[10];

  char* ws = (char*)d_ws;
  short* Xb    = (short*)(ws + 0);          // 16,777,216 B
  short* WcatT = (short*)(ws + 16777216);   //  1,572,864 B
  short* WpT   = (short*)(ws + 18350080);   //    524,288 B
  float* bcat  = (float*)(ws + 18874368);   //      3,072 B (pad to 4096)
  short* O     = (short*)(ws + 18878464);   // 12,582,912 B  (QKVG bf16)
  short* Vtp   = (short*)(ws + 31461376);   //  4,194,304 B
  float* q2a   = (float*)(ws + 35655680);   //     32,768 B
  float* k2a   = (float*)(ws + 35688448);   //     32,768 B
  short* AG    = (short*)(ws + 35721216);   //  4,194,304 B  (total ~39.9 MB)
  // Aliases: dead after k_gemm1, reused by split-K attention partials.
  short* nump  = (short*)(ws + 0);          // 16,777,216 B over Xb
  float* denp  = (float*)(ws + 16777216);   //    131,072 B over WcatT
  float* Y = (float*)d_out;

  hipLaunchKernelGGL(k_prep, dim3(4353), dim3(256), 0, stream,
                     X, Wq, bq, Wk, bk, Wv, bv, Wg, bg, Wp, Xb, WcatT, WpT, bcat);
  hipLaunchKernelGGL(k_gemm1, dim3(64, 6), dim3(256), 0, stream, Xb, WcatT, bcat, O, q2a, k2a);
  hipLaunchKernelGGL(k_vt, dim3(1024), dim3(256), 0, stream, O, Vtp);
  hipLaunchKernelGGL(k_attn, dim3(1024), dim3(256), 0, stream, O, Vtp, q2a, k2a, nump, denp);
  hipLaunchKernelGGL(k_red, dim3(1024), dim3(256), 0, stream, nump, denp, O, AG);
  hipLaunchKernelGGL(k_gemm3, dim3(64, 8), dim3(256), 0, stream, AG, WpT, X, bp, Y);
}

// Round 7
// 256.889 us; speedup vs baseline: 1.2686x; 1.2686x over previous
//
#include <hip/hip_runtime.h>
#include <stdint.h>

// Problem sizes (fixed): B=4, S=2048, D=1024, DQK=128, DV=256
#define SLEN 2048
#define NROWS 8192   // B*S

typedef __attribute__((ext_vector_type(4))) float f32x4;
typedef __attribute__((ext_vector_type(8))) short bf16x8;
typedef __attribute__((ext_vector_type(2))) unsigned int u32x2;
typedef __attribute__((ext_vector_type(4))) unsigned int u32x4;

__device__ __forceinline__ short f2bf(float f) {
  uint32_t u = __builtin_bit_cast(uint32_t, f);
  u += 0x7FFFu + ((u >> 16) & 1u);
  return (short)(u >> 16);
}
__device__ __forceinline__ float bf2f(short s) {
  uint32_t u = ((uint32_t)(uint16_t)s) << 16;
  return __builtin_bit_cast(float, u);
}
__device__ __forceinline__ f32x4 mfma16(bf16x8 a, bf16x8 b, f32x4 c) {
  return __builtin_amdgcn_mfma_f32_16x16x32_bf16(a, b, c, 0, 0, 0);
}
__device__ __forceinline__ void gld_lds16(const void* g, void* l) {
  __builtin_amdgcn_global_load_lds(
      (const __attribute__((address_space(1))) void*)g,
      (__attribute__((address_space(3))) void*)l, 16, 0, 0);
}

// ---------------------------------------------------------------- prep ------
__global__ __launch_bounds__(256) void k_prep(
    const float* __restrict__ X,
    const float* __restrict__ Wq, const float* __restrict__ bq,
    const float* __restrict__ Wk, const float* __restrict__ bk,
    const float* __restrict__ Wv, const float* __restrict__ bv,
    const float* __restrict__ Wg, const float* __restrict__ bg,
    const float* __restrict__ Wp,
    short* __restrict__ Xb, short* __restrict__ WcatT,
    short* __restrict__ WpT, float* __restrict__ bcat) {
  __shared__ short tl[64][72];
  int blk = blockIdx.x, tid = threadIdx.x;
  if (blk < 4096) {
    size_t e = ((size_t)blk * 256 + tid) * 8;
    f32x4 a = *(const f32x4*)&X[e];
    f32x4 b = *(const f32x4*)&X[e + 4];
    bf16x8 o;
    o[0] = f2bf(a[0]); o[1] = f2bf(a[1]); o[2] = f2bf(a[2]); o[3] = f2bf(a[3]);
    o[4] = f2bf(b[0]); o[5] = f2bf(b[1]); o[6] = f2bf(b[2]); o[7] = f2bf(b[3]);
    *(bf16x8*)&Xb[e] = o;
  } else if (blk < 4352) {
    int t = blk - 4096;
    const float* src; short* dst; int C, rowoff, dstC, r0, c0;
    if (t < 32)       { src = Wq; C = 128;  rowoff = 0;   dst = WcatT; dstC = 1024; r0 = (t >> 1) * 64;  c0 = (t & 1) * 64; }
    else if (t < 64)  { t -= 32;  src = Wk; C = 128;  rowoff = 128; dst = WcatT; dstC = 1024; r0 = (t >> 1) * 64;  c0 = (t & 1) * 64; }
    else if (t < 128) { t -= 64;  src = Wv; C = 256;  rowoff = 256; dst = WcatT; dstC = 1024; r0 = (t >> 2) * 64;  c0 = (t & 3) * 64; }
    else if (t < 192) { t -= 128; src = Wg; C = 256;  rowoff = 512; dst = WcatT; dstC = 1024; r0 = (t >> 2) * 64;  c0 = (t & 3) * 64; }
    else              { t -= 192; src = Wp; C = 1024; rowoff = 0;   dst = WpT;   dstC = 256;  r0 = (t >> 4) * 64;  c0 = (t & 15) * 64; }
    int lr = tid >> 4, lcc = tid & 15;
#pragma unroll
    for (int rr = 0; rr < 4; ++rr) {
      f32x4 v = *(const f32x4*)&src[(size_t)(r0 + lr * 4 + rr) * C + c0 + lcc * 4];
#pragma unroll
      for (int j = 0; j < 4; ++j) tl[lcc * 4 + j][lr * 4 + rr] = f2bf(v[j]);
    }
    __syncthreads();
    int orow = tid >> 2, og = (tid & 3) * 16;
    bf16x8 o1, o2;
#pragma unroll
    for (int j = 0; j < 8; ++j) { o1[j] = tl[orow][og + j]; o2[j] = tl[orow][og + 8 + j]; }
    size_t dbase = (size_t)(rowoff + c0 + orow) * dstC + r0 + og;
    *(bf16x8*)&dst[dbase] = o1;
    *(bf16x8*)&dst[dbase + 8] = o2;
  } else {
    int c = tid;
    if (c < 768) {
      float v;
      if (c < 128)      v = bq[c];
      else if (c < 256) v = bk[c - 128];
      else if (c < 512) v = bv[c - 256];
      else              v = bg[c - 512];
      bcat[c] = v;
    }
  }
}

// ---------------------------------------------------------------- gemm1 -----
// O[8192][768] = Xb[8192][1024] @ Wcat + bcat. Blocks with y==0/1 also emit
// q2a/k2a row norms (sum over the 128 Q/K cols of bf16-rounded values).
__global__ __launch_bounds__(256) void k_gemm1(
    const short* __restrict__ Xb, const short* __restrict__ WcatT,
    const float* __restrict__ bcat, short* __restrict__ O,
    float* __restrict__ q2a, float* __restrict__ k2a) {
  __shared__ short At[128 * 32];
  __shared__ short Bt[128 * 32];
  __shared__ float nlds[128][2];
  const int tid = threadIdx.x;
  const int w = tid >> 6, l = tid & 63, lg = l >> 4, lc = l & 15;
  const int m0 = blockIdx.x * 128, n0 = blockIdx.y * 128;
  const int sr0 = w * 32 + (l >> 2);
  const int scc = (l & 3) * 8;
  const int wm = (w >> 1) * 64, wn = (w & 1) * 64;

  f32x4 acc[4][4] = {};
  const short* Ab = Xb + (size_t)m0 * 1024;
  const short* Bb = WcatT + (size_t)n0 * 1024;

  for (int kb = 0; kb < 1024; kb += 32) {
    gld_lds16(Ab + (size_t)sr0 * 1024 + kb + scc, &At[(w * 32) * 32]);
    gld_lds16(Ab + (size_t)(sr0 + 16) * 1024 + kb + scc, &At[(w * 32 + 16) * 32]);
    gld_lds16(Bb + (size_t)sr0 * 1024 + kb + scc, &Bt[(w * 32) * 32]);
    gld_lds16(Bb + (size_t)(sr0 + 16) * 1024 + kb + scc, &Bt[(w * 32 + 16) * 32]);
    __syncthreads();
    bf16x8 af[4], bf[4];
#pragma unroll
    for (int mi = 0; mi < 4; ++mi)
      af[mi] = *(const bf16x8*)&At[(wm + mi * 16 + lc) * 32 + lg * 8];
#pragma unroll
    for (int ni = 0; ni < 4; ++ni)
      bf[ni] = *(const bf16x8*)&Bt[(wn + ni * 16 + lc) * 32 + lg * 8];
#pragma unroll
    for (int mi = 0; mi < 4; ++mi)
#pragma unroll
      for (int ni = 0; ni < 4; ++ni)
        acc[mi][ni] = mfma16(af[mi], bf[ni], acc[mi][ni]);
    __syncthreads();
  }
  float sq[4][4] = {};
#pragma unroll
  for (int mi = 0; mi < 4; ++mi) {
    int gr = m0 + wm + mi * 16 + lg * 4;
#pragma unroll
    for (int ni = 0; ni < 4; ++ni) {
      int gc = n0 + wn + ni * 16 + lc;
      float bias = bcat[gc];
#pragma unroll
      for (int r = 0; r < 4; ++r) {
        short sv = f2bf(acc[mi][ni][r] + bias);
        O[(size_t)(gr + r) * 768 + gc] = sv;
        float v = bf2f(sv);
        sq[mi][r] += v * v;
      }
    }
  }
  if (blockIdx.y < 2) {
#pragma unroll
    for (int mi = 0; mi < 4; ++mi)
#pragma unroll
      for (int r = 0; r < 4; ++r) {
        float v = sq[mi][r];
        v += __shfl_xor(v, 1, 64); v += __shfl_xor(v, 2, 64);
        v += __shfl_xor(v, 4, 64); v += __shfl_xor(v, 8, 64);
        sq[mi][r] = v;
      }
    if (lc == 0) {
#pragma unroll
      for (int mi = 0; mi < 4; ++mi)
#pragma unroll
        for (int r = 0; r < 4; ++r)
          nlds[wm + mi * 16 + lg * 4 + r][w & 1] = sq[mi][r];
    }
    __syncthreads();
    if (tid < 128) {
      float t = nlds[tid][0] + nlds[tid][1];
      (blockIdx.y == 0 ? q2a : k2a)[m0 + tid] = t;
    }
  }
}

// ---------------------------------------------------------------- vt --------
// Vtp: V transposed AND k-permuted to match the in-register P fragment:
// pos(k) = (k>>5)*32 + ((k>>2)&3)*8 + ((k>>4)&1)*4 + (k&3)
__global__ __launch_bounds__(256) void k_vt(
    const short* __restrict__ O, short* __restrict__ Vtp) {
  __shared__ short tile[64][33];
  int blk = blockIdx.x, tid = threadIdx.x;
  int b = blk >> 8, rem = blk & 255;
  int s0 = (rem >> 3) * 64, dv0 = (rem & 7) * 32;
  int r = tid >> 2, cg = (tid & 3) * 8;
  bf16x8 v = *(const bf16x8*)&O[(size_t)(b * SLEN + s0 + r) * 768 + 256 + dv0 + cg];
#pragma unroll
  for (int j = 0; j < 8; ++j) tile[r][cg + j] = v[j];
  __syncthreads();
  int dr = tid >> 3, sg = (tid & 7) * 8;
  bf16x8 ov;
#pragma unroll
  for (int j = 0; j < 8; ++j) ov[j] = tile[sg + j][dr];
  int ka = s0 + sg;
  int c5 = ka >> 5, hi = (ka >> 4) & 1, lgq = (ka >> 2) & 3;
  size_t base = (size_t)(b * 256 + dv0 + dr) * SLEN + c5 * 32 + lgq * 8 + hi * 4;
  u32x4 od = __builtin_bit_cast(u32x4, ov);
  u32x2 p0; p0[0] = od[0]; p0[1] = od[1];
  u32x2 p1; p1[0] = od[2]; p1[1] = od[3];
  *(u32x2*)&Vtp[base] = p0;        // k = ka..ka+3
  *(u32x2*)&Vtp[base + 8] = p1;    // k = ka+4..ka+7
}

// ---------------------------------------------------------------- attn ------
// Grid 2048: gid -> (b, qt, ks, dvh). Block = 4 waves, 32q x 512k x 128dv.
// Wave w: kh = w>>1 (256k), dvq = w&1 (64dv). acc[2][4] = 32 regs/lane.
// No launch_bounds min (round-6 lesson: forcing waves/EU past the live set
// spills ~600 MB to scratch). Epilogue: kh=1 stash bf16 (8 KB), kh=0 combine.
__global__ __launch_bounds__(256) void k_attn(
    const short* __restrict__ O, const short* __restrict__ Vtp,
    const float* __restrict__ q2a, const float* __restrict__ k2a,
    short* __restrict__ nump, float* __restrict__ denp) {
  __shared__ __align__(16) short stash[2][8][64][4];  // [dvq][combo][lane][r]
  __shared__ float dls[2][32];
  const int tid = threadIdx.x;
  const int w = tid >> 6, l = tid & 63, lg = l >> 4, lc = l & 15;
  const int kh = w >> 1, dvq = w & 1;
  const int gid = blockIdx.x;
  const int blk2 = ((gid & 7) << 8) | (gid >> 3);  // XCD swizzle (2048%8==0)
  const int b = blk2 >> 9;
  const int rr_ = blk2 & 511;
  const int qt = rr_ >> 3, ks = (rr_ >> 1) & 3, dvh = rr_ & 1;
  const int grow0 = b * SLEN + qt * 32;
  const int kloc0 = ks * 512 + kh * 256;      // within-batch k base for wave
  const int krow0 = b * SLEN + kloc0;

  bf16x8 qf[2][4];
#pragma unroll
  for (int mi = 0; mi < 2; ++mi)
#pragma unroll
    for (int kf = 0; kf < 4; ++kf)
      qf[mi][kf] = *(const bf16x8*)&O[(size_t)(grow0 + mi * 16 + lc) * 768 + kf * 32 + lg * 8];

  float q2s[2];
  q2s[0] = q2a[grow0 + lc];
  q2s[1] = q2a[grow0 + 16 + lc];

  f32x4 acc[2][4] = {};
  float den0 = 0.f, den1 = 0.f;
  const short* vbase = Vtp + (size_t)(b * 256 + dvh * 128 + dvq * 64 + lc) * SLEN;

#pragma unroll 2
  for (int c = 0; c < 8; ++c) {
    const int kr = krow0 + c * 32;
    f32x4 s[2][2] = {};
#pragma unroll
    for (int e = 0; e < 2; ++e)
#pragma unroll
      for (int kf = 0; kf < 4; ++kf) {
        bf16x8 kv = *(const bf16x8*)&O[(size_t)(kr + e * 16 + lc) * 768 + 128 + kf * 32 + lg * 8];
        s[0][e] = mfma16(kv, qf[0][kf], s[0][e]);   // swapped: D[k][q]
        s[1][e] = mfma16(kv, qf[1][kf], s[1][e]);
      }
    float wv[2][2][4];
#pragma unroll
    for (int e = 0; e < 2; ++e) {
      f32x4 k2v = *(const f32x4*)&k2a[kr + e * 16 + lg * 4];
#pragma unroll
      for (int mi = 0; mi < 2; ++mi)
#pragma unroll
        for (int r = 0; r < 4; ++r) {
          float d2 = q2s[mi] + k2v[r] - 2.0f * s[mi][e][r];
          wv[mi][e][r] = __builtin_amdgcn_rcpf(fmaxf(d2, 1e-16f));
        }
    }
#pragma unroll
    for (int r = 0; r < 4; ++r) {
      den0 += wv[0][0][r] + wv[0][1][r];
      den1 += wv[1][0][r] + wv[1][1][r];
    }
    bf16x8 pa[2];
#pragma unroll
    for (int mi = 0; mi < 2; ++mi) {
#pragma unroll
      for (int r = 0; r < 4; ++r) {
        pa[mi][r] = f2bf(wv[mi][0][r]);      // slots 0-3: k = lg*4+r
        pa[mi][4 + r] = f2bf(wv[mi][1][r]);  // slots 4-7: k = 16+lg*4+r
      }
    }
    const int voff = kloc0 + c * 32 + lg * 8;
#pragma unroll
    for (int nv = 0; nv < 4; ++nv) {
      bf16x8 bv = *(const bf16x8*)&vbase[(size_t)nv * 16 * SLEN + voff];
      acc[0][nv] = mfma16(pa[0], bv, acc[0][nv]);
      acc[1][nv] = mfma16(pa[1], bv, acc[1][nv]);
    }
  }
  // den: reduce over lg groups within wave; dvq==0 waves publish per-k-half
  den0 += __shfl_xor(den0, 16, 64); den0 += __shfl_xor(den0, 32, 64);
  den1 += __shfl_xor(den1, 16, 64); den1 += __shfl_xor(den1, 32, 64);
  if (dvq == 0 && l < 16) { dls[kh][l] = den0; dls[kh][16 + l] = den1; }
  // kh==1 waves stash bf16 partials
  if (kh == 1) {
#pragma unroll
    for (int mi = 0; mi < 2; ++mi)
#pragma unroll
      for (int nv = 0; nv < 4; ++nv) {
        f32x4 a = acc[mi][nv];
        u32x2 pk;
        pk[0] = (uint32_t)(uint16_t)f2bf(a[0]) | ((uint32_t)(uint16_t)f2bf(a[1]) << 16);
        pk[1] = (uint32_t)(uint16_t)f2bf(a[2]) | ((uint32_t)(uint16_t)f2bf(a[3]) << 16);
        *(u32x2*)&stash[dvq][mi * 4 + nv][l][0] = pk;
      }
  }
  __syncthreads();
  if (kh == 0) {
    const size_t pbase = (size_t)((b * 64 + qt) * 4 + ks) * 32 * 256;
#pragma unroll
    for (int mi = 0; mi < 2; ++mi)
#pragma unroll
      for (int nv = 0; nv < 4; ++nv) {
        u32x2 sv = *(const u32x2*)&stash[dvq][mi * 4 + nv][l][0];
        f32x4 a = acc[mi][nv];
        a[0] += bf2f((short)(sv[0] & 0xFFFFu));
        a[1] += bf2f((short)(sv[0] >> 16));
        a[2] += bf2f((short)(sv[1] & 0xFFFFu));
        a[3] += bf2f((short)(sv[1] >> 16));
        int dv = dvh * 128 + dvq * 64 + nv * 16 + lc;
        int rb = mi * 16 + lg * 4;
#pragma unroll
        for (int r = 0; r < 4; ++r)
          nump[pbase + (size_t)(rb + r) * 256 + dv] = f2bf(a[r]);
      }
  }
  if (dvh == 0 && tid < 32) {
    int pb = (b * 64 + qt) * 4 + ks;
    denp[pb * 32 + tid] = dls[0][tid] + dls[1][tid];
  }
}

// ---------------------------------------------------------------- red -------
// AG[row][dv] = (sum_ks nump) / (sum_ks denp) * G[row][dv]
__global__ __launch_bounds__(256) void k_red(
    const short* __restrict__ nump, const float* __restrict__ denp,
    const short* __restrict__ O, short* __restrict__ AG) {
  int flat = blockIdx.x * 256 + threadIdx.x;   // 0..262143
  int idx8 = flat * 8;
  int row = idx8 >> 8;
  int dv0 = idx8 & 255;
  int b = row >> 11, srow = row & 2047;
  int qt = srow >> 5, rit = srow & 31;
  int blkbase = (b * 64 + qt) << 2;
  float num[8] = {};
  float den = 0.f;
#pragma unroll
  for (int ksi = 0; ksi < 4; ++ksi) {
    const size_t base = ((size_t)(blkbase + ksi) * 32 + rit) * 256 + dv0;
    bf16x8 v = *(const bf16x8*)&nump[base];
#pragma unroll
    for (int j = 0; j < 8; ++j) num[j] += bf2f(v[j]);
    den += denp[(blkbase + ksi) * 32 + rit];
  }
  float rden = 1.f / den;
  bf16x8 gv = *(const bf16x8*)&O[(size_t)row * 768 + 512 + dv0];
  bf16x8 o;
#pragma unroll
  for (int j = 0; j < 8; ++j) o[j] = f2bf(num[j] * rden * bf2f(gv[j]));
  *(bf16x8*)&AG[idx8] = o;
}

// ---------------------------------------------------------------- gemm3 -----
// Y[8192][1024] = X + AG[8192][256] @ Wp + bp
__global__ __launch_bounds__(256) void k_gemm3(
    const short* __restrict__ AG, const short* __restrict__ WpT,
    const float* __restrict__ X, const float* __restrict__ bp,
    float* __restrict__ Y) {
  __shared__ short At[128 * 32];
  __shared__ short Bt[128 * 32];
  const int tid = threadIdx.x;
  const int w = tid >> 6, l = tid & 63, lg = l >> 4, lc = l & 15;
  const int m0 = blockIdx.x * 128, n0 = blockIdx.y * 128;
  const int sr0 = w * 32 + (l >> 2);
  const int scc = (l & 3) * 8;
  const int wm = (w >> 1) * 64, wn = (w & 1) * 64;

  f32x4 acc[4][4] = {};
  const short* Ab = AG + (size_t)m0 * 256;
  const short* Bb = WpT + (size_t)n0 * 256;

  for (int kb = 0; kb < 256; kb += 32) {
    gld_lds16(Ab + (size_t)sr0 * 256 + kb + scc, &At[(w * 32) * 32]);
    gld_lds16(Ab + (size_t)(sr0 + 16) * 256 + kb + scc, &At[(w * 32 + 16) * 32]);
    gld_lds16(Bb + (size_t)sr0 * 256 + kb + scc, &Bt[(w * 32) * 32]);
    gld_lds16(Bb + (size_t)(sr0 + 16) * 256 + kb + scc, &Bt[(w * 32 + 16) * 32]);
    __syncthreads();
    bf16x8 af[4], bf[4];
#pragma unroll
    for (int mi = 0; mi < 4; ++mi)
      af[mi] = *(const bf16x8*)&At[(wm + mi * 16 + lc) * 32 + lg * 8];
#pragma unroll
    for (int ni = 0; ni < 4; ++ni)
      bf[ni] = *(const bf16x8*)&Bt[(wn + ni * 16 + lc) * 32 + lg * 8];
#pragma unroll
    for (int mi = 0; mi < 4; ++mi)
#pragma unroll
      for (int ni = 0; ni < 4; ++ni)
        acc[mi][ni] = mfma16(af[mi], bf[ni], acc[mi][ni]);
    __syncthreads();
  }
#pragma unroll
  for (int mi = 0; mi < 4; ++mi) {
    int gr = m0 + wm + mi * 16 + lg * 4;
#pragma unroll
    for (int ni = 0; ni < 4; ++ni) {
      int gc = n0 + wn + ni * 16 + lc;
      float bias = bp[gc];
#pragma unroll
      for (int r = 0; r < 4; ++r) {
        size_t idx = (size_t)(gr + r) * 1024 + gc;
        Y[idx] = acc[mi][ni][r] + X[idx] + bias;
      }
    }
  }
}

// ---------------------------------------------------------------- launch ----
extern "C" void kernel_launch(void* const* d_in, const int* in_sizes, int n_in,
                              void* d_out, int out_size, void* d_ws, size_t ws_size,
                              hipStream_t stream) {
  const float* X  = (const float*)d_in[0];
  const float* Wq = (const float*)d_in[1];
  const float* bq = (const float*)d_in[2];
  const float* Wk = (const float*)d_in[3];
  const float* bk = (const float*)d_in[4];
  const float* Wv = (const float*)d_in[5];
  const float* bv = (const float*)d_in[6];
  const float* Wg = (const float*)d_in[7];
  const float* bg = (const float*)d_in[8];
  const float* Wp = (const float*)d_in[9];
  const float* bp = (const float*)d_in[10];

  char* ws = (char*)d_ws;
  short* Xb    = (short*)(ws + 0);          // 16,777,216 B
  short* WcatT = (short*)(ws + 16777216);   //  1,572,864 B
  short* WpT   = (short*)(ws + 18350080);   //    524,288 B
  float* bcat  = (float*)(ws + 18874368);   //      3,072 B (pad to 4096)
  short* O     = (short*)(ws + 18878464);   // 12,582,912 B  (QKVG bf16)
  short* Vtp   = (short*)(ws + 31461376);   //  4,194,304 B
  float* q2a   = (float*)(ws + 35655680);   //     32,768 B
  float* k2a   = (float*)(ws + 35688448);   //     32,768 B
  short* AG    = (short*)(ws + 35721216);   //  4,194,304 B  (total ~39.9 MB)
  // Aliases: dead after k_gemm1, reused by split-K attention partials.
  short* nump  = (short*)(ws + 0);          // 16,777,216 B over Xb
  float* denp  = (float*)(ws + 16777216);   //    131,072 B over WcatT
  float* Y = (float*)d_out;

  hipLaunchKernelGGL(k_prep, dim3(4353), dim3(256), 0, stream,
                     X, Wq, bq, Wk, bk, Wv, bv, Wg, bg, Wp, Xb, WcatT, WpT, bcat);
  hipLaunchKernelGGL(k_gemm1, dim3(64, 6), dim3(256), 0, stream, Xb, WcatT, bcat, O, q2a, k2a);
  hipLaunchKernelGGL(k_vt, dim3(1024), dim3(256), 0, stream, O, Vtp);
  hipLaunchKernelGGL(k_attn, dim3(2048), dim3(256), 0, stream, O, Vtp, q2a, k2a, nump, denp);
  hipLaunchKernelGGL(k_red, dim3(1024), dim3(256), 0, stream, nump, denp, O, AG);
  hipLaunchKernelGGL(k_gemm3, dim3(64, 8), dim3(256), 0, stream, AG, WpT, X, bp, Y);
}

// Round 8
// 179.376 us; speedup vs baseline: 1.8169x; 1.4321x over previous
//
#include <hip/hip_runtime.h>
#include <stdint.h>

// Problem sizes (fixed): B=4, S=2048, D=1024, DQK=128, DV=256
#define SLEN 2048
#define NROWS 8192   // B*S

typedef __attribute__((ext_vector_type(4))) float f32x4;
typedef __attribute__((ext_vector_type(8))) short bf16x8;
typedef __attribute__((ext_vector_type(2))) unsigned int u32x2;
typedef __attribute__((ext_vector_type(4))) unsigned int u32x4;

__device__ __forceinline__ short f2bf(float f) {
  uint32_t u = __builtin_bit_cast(uint32_t, f);
  u += 0x7FFFu + ((u >> 16) & 1u);
  return (short)(u >> 16);
}
__device__ __forceinline__ float bf2f(short s) {
  uint32_t u = ((uint32_t)(uint16_t)s) << 16;
  return __builtin_bit_cast(float, u);
}
__device__ __forceinline__ f32x4 mfma16(bf16x8 a, bf16x8 b, f32x4 c) {
  return __builtin_amdgcn_mfma_f32_16x16x32_bf16(a, b, c, 0, 0, 0);
}
__device__ __forceinline__ void gld_lds16(const void* g, void* l) {
  __builtin_amdgcn_global_load_lds(
      (const __attribute__((address_space(1))) void*)g,
      (__attribute__((address_space(3))) void*)l, 16, 0, 0);
}

// ---------------------------------------------------------------- prep ------
__global__ __launch_bounds__(256) void k_prep(
    const float* __restrict__ X,
    const float* __restrict__ Wq, const float* __restrict__ bq,
    const float* __restrict__ Wk, const float* __restrict__ bk,
    const float* __restrict__ Wv, const float* __restrict__ bv,
    const float* __restrict__ Wg, const float* __restrict__ bg,
    const float* __restrict__ Wp,
    short* __restrict__ Xb, short* __restrict__ WcatT,
    short* __restrict__ WpT, float* __restrict__ bcat) {
  __shared__ short tl[64][72];
  int blk = blockIdx.x, tid = threadIdx.x;
  if (blk < 4096) {
    size_t e = ((size_t)blk * 256 + tid) * 8;
    f32x4 a = *(const f32x4*)&X[e];
    f32x4 b = *(const f32x4*)&X[e + 4];
    bf16x8 o;
    o[0] = f2bf(a[0]); o[1] = f2bf(a[1]); o[2] = f2bf(a[2]); o[3] = f2bf(a[3]);
    o[4] = f2bf(b[0]); o[5] = f2bf(b[1]); o[6] = f2bf(b[2]); o[7] = f2bf(b[3]);
    *(bf16x8*)&Xb[e] = o;
  } else if (blk < 4352) {
    int t = blk - 4096;
    const float* src; short* dst; int C, rowoff, dstC, r0, c0;
    if (t < 32)       { src = Wq; C = 128;  rowoff = 0;   dst = WcatT; dstC = 1024; r0 = (t >> 1) * 64;  c0 = (t & 1) * 64; }
    else if (t < 64)  { t -= 32;  src = Wk; C = 128;  rowoff = 128; dst = WcatT; dstC = 1024; r0 = (t >> 1) * 64;  c0 = (t & 1) * 64; }
    else if (t < 128) { t -= 64;  src = Wv; C = 256;  rowoff = 256; dst = WcatT; dstC = 1024; r0 = (t >> 2) * 64;  c0 = (t & 3) * 64; }
    else if (t < 192) { t -= 128; src = Wg; C = 256;  rowoff = 512; dst = WcatT; dstC = 1024; r0 = (t >> 2) * 64;  c0 = (t & 3) * 64; }
    else              { t -= 192; src = Wp; C = 1024; rowoff = 0;   dst = WpT;   dstC = 256;  r0 = (t >> 4) * 64;  c0 = (t & 15) * 64; }
    int lr = tid >> 4, lcc = tid & 15;
#pragma unroll
    for (int rr = 0; rr < 4; ++rr) {
      f32x4 v = *(const f32x4*)&src[(size_t)(r0 + lr * 4 + rr) * C + c0 + lcc * 4];
#pragma unroll
      for (int j = 0; j < 4; ++j) tl[lcc * 4 + j][lr * 4 + rr] = f2bf(v[j]);
    }
    __syncthreads();
    int orow = tid >> 2, og = (tid & 3) * 16;
    bf16x8 o1, o2;
#pragma unroll
    for (int j = 0; j < 8; ++j) { o1[j] = tl[orow][og + j]; o2[j] = tl[orow][og + 8 + j]; }
    size_t dbase = (size_t)(rowoff + c0 + orow) * dstC + r0 + og;
    *(bf16x8*)&dst[dbase] = o1;
    *(bf16x8*)&dst[dbase + 8] = o2;
  } else {
    int c = tid;
    if (c < 768) {
      float v;
      if (c < 128)      v = bq[c];
      else if (c < 256) v = bk[c - 128];
      else if (c < 512) v = bv[c - 256];
      else              v = bg[c - 512];
      bcat[c] = v;
    }
  }
}

// ---------------------------------------------------------------- gemm1 -----
__global__ __launch_bounds__(256) void k_gemm1(
    const short* __restrict__ Xb, const short* __restrict__ WcatT,
    const float* __restrict__ bcat, short* __restrict__ O,
    float* __restrict__ q2a, float* __restrict__ k2a) {
  __shared__ short At[128 * 32];
  __shared__ short Bt[128 * 32];
  __shared__ float nlds[128][2];
  const int tid = threadIdx.x;
  const int w = tid >> 6, l = tid & 63, lg = l >> 4, lc = l & 15;
  const int m0 = blockIdx.x * 128, n0 = blockIdx.y * 128;
  const int sr0 = w * 32 + (l >> 2);
  const int scc = (l & 3) * 8;
  const int wm = (w >> 1) * 64, wn = (w & 1) * 64;

  f32x4 acc[4][4] = {};
  const short* Ab = Xb + (size_t)m0 * 1024;
  const short* Bb = WcatT + (size_t)n0 * 1024;

  for (int kb = 0; kb < 1024; kb += 32) {
    gld_lds16(Ab + (size_t)sr0 * 1024 + kb + scc, &At[(w * 32) * 32]);
    gld_lds16(Ab + (size_t)(sr0 + 16) * 1024 + kb + scc, &At[(w * 32 + 16) * 32]);
    gld_lds16(Bb + (size_t)sr0 * 1024 + kb + scc, &Bt[(w * 32) * 32]);
    gld_lds16(Bb + (size_t)(sr0 + 16) * 1024 + kb + scc, &Bt[(w * 32 + 16) * 32]);
    __syncthreads();
    bf16x8 af[4], bf[4];
#pragma unroll
    for (int mi = 0; mi < 4; ++mi)
      af[mi] = *(const bf16x8*)&At[(wm + mi * 16 + lc) * 32 + lg * 8];
#pragma unroll
    for (int ni = 0; ni < 4; ++ni)
      bf[ni] = *(const bf16x8*)&Bt[(wn + ni * 16 + lc) * 32 + lg * 8];
#pragma unroll
    for (int mi = 0; mi < 4; ++mi)
#pragma unroll
      for (int ni = 0; ni < 4; ++ni)
        acc[mi][ni] = mfma16(af[mi], bf[ni], acc[mi][ni]);
    __syncthreads();
  }
  float sq[4][4] = {};
#pragma unroll
  for (int mi = 0; mi < 4; ++mi) {
    int gr = m0 + wm + mi * 16 + lg * 4;
#pragma unroll
    for (int ni = 0; ni < 4; ++ni) {
      int gc = n0 + wn + ni * 16 + lc;
      float bias = bcat[gc];
#pragma unroll
      for (int r = 0; r < 4; ++r) {
        short sv = f2bf(acc[mi][ni][r] + bias);
        O[(size_t)(gr + r) * 768 + gc] = sv;
        float v = bf2f(sv);
        sq[mi][r] += v * v;
      }
    }
  }
  if (blockIdx.y < 2) {
#pragma unroll
    for (int mi = 0; mi < 4; ++mi)
#pragma unroll
      for (int r = 0; r < 4; ++r) {
        float v = sq[mi][r];
        v += __shfl_xor(v, 1, 64); v += __shfl_xor(v, 2, 64);
        v += __shfl_xor(v, 4, 64); v += __shfl_xor(v, 8, 64);
        sq[mi][r] = v;
      }
    if (lc == 0) {
#pragma unroll
      for (int mi = 0; mi < 4; ++mi)
#pragma unroll
        for (int r = 0; r < 4; ++r)
          nlds[wm + mi * 16 + lg * 4 + r][w & 1] = sq[mi][r];
    }
    __syncthreads();
    if (tid < 128) {
      float t = nlds[tid][0] + nlds[tid][1];
      (blockIdx.y == 0 ? q2a : k2a)[m0 + tid] = t;
    }
  }
}

// ---------------------------------------------------------------- vt --------
// Vtp: V transposed AND k-permuted to match the in-register P fragment:
// pos(k) = (k>>5)*32 + ((k>>2)&3)*8 + ((k>>4)&1)*4 + (k&3)
__global__ __launch_bounds__(256) void k_vt(
    const short* __restrict__ O, short* __restrict__ Vtp) {
  __shared__ short tile[64][33];
  int blk = blockIdx.x, tid = threadIdx.x;
  int b = blk >> 8, rem = blk & 255;
  int s0 = (rem >> 3) * 64, dv0 = (rem & 7) * 32;
  int r = tid >> 2, cg = (tid & 3) * 8;
  bf16x8 v = *(const bf16x8*)&O[(size_t)(b * SLEN + s0 + r) * 768 + 256 + dv0 + cg];
#pragma unroll
  for (int j = 0; j < 8; ++j) tile[r][cg + j] = v[j];
  __syncthreads();
  int dr = tid >> 3, sg = (tid & 7) * 8;
  bf16x8 ov;
#pragma unroll
  for (int j = 0; j < 8; ++j) ov[j] = tile[sg + j][dr];
  int ka = s0 + sg;
  int c5 = ka >> 5, hi = (ka >> 4) & 1, lgq = (ka >> 2) & 3;
  size_t base = (size_t)(b * 256 + dv0 + dr) * SLEN + c5 * 32 + lgq * 8 + hi * 4;
  u32x4 od = __builtin_bit_cast(u32x4, ov);
  u32x2 p0; p0[0] = od[0]; p0[1] = od[1];
  u32x2 p1; p1[0] = od[2]; p1[1] = od[3];
  *(u32x2*)&Vtp[base] = p0;        // k = ka..ka+3
  *(u32x2*)&Vtp[base + 8] = p1;    // k = ka+4..ka+7
}

// ---------------------------------------------------------------- attn ------
// m214-style: 8 waves/block (512 thr), 128 q rows (16/wave), k-window 512
// (ks split 4), all 256 dv per wave. K-tile [64][128] + Vtp-tile [256][64]
// double-buffered in LDS (96 KB), staged via global_load_lds with
// pre-swizzled SOURCE (linear dest) + XOR-swizzled ds_read_b128.
// One barrier per tile; stage(t+1) issued before compute(t).
__global__ __launch_bounds__(512) void k_attn(
    const short* __restrict__ O, const short* __restrict__ Vtp,
    const float* __restrict__ q2a, const float* __restrict__ k2a,
    short* __restrict__ nump, float* __restrict__ denp) {
  __shared__ short Klds[2][64 * 128];    // 16 KB each
  __shared__ short Vlds[2][256 * 64];    // 32 KB each  (total 96 KB)
  const int tid = threadIdx.x;
  const int w = tid >> 6, l = tid & 63, lg = l >> 4, lc = l & 15;
  const int gid = blockIdx.x;
  const int blk = ((gid & 7) << 5) | (gid >> 3);   // XCD swizzle (256%8==0)
  const int b = blk >> 6, qt = (blk >> 2) & 15, ks = blk & 3;
  const int grow0 = b * SLEN + qt * 128 + w * 16;  // wave's 16 q rows
  const int kbase = ks * 512;

  // Q frags (B-operand: col=q=lc, slots = dqk)
  bf16x8 qf[4];
#pragma unroll
  for (int kf = 0; kf < 4; ++kf)
    qf[kf] = *(const bf16x8*)&O[(size_t)(grow0 + lc) * 768 + kf * 32 + lg * 8];
  const float q2s = q2a[grow0 + lc];

  f32x4 acc[16] = {};     // [nv]: q = lg*4+r, dv = nv*16+lc
  float den = 0.f;

  // --- staging: 48 issues/tile (16 K + 32 V), 6 per wave, linear LDS dest,
  // global source pre-swizzled so swizzled ds_reads see logical data.
#define STAGE(T, BSEL)                                                        \
  {                                                                           \
    const int kt_ = kbase + (T) * 64;                                         \
    _Pragma("unroll")                                                         \
    for (int j = 0; j < 6; ++j) {                                             \
      int issue = w * 6 + j;                                                  \
      if (issue < 16) {                                                       \
        int kk = issue * 4 + (l >> 4);                                        \
        int c = l & 15;                                                       \
        const short* src = O + (size_t)(b * SLEN + kt_ + kk) * 768 + 128 +    \
                           ((c ^ (kk & 7)) * 8);                              \
        gld_lds16(src, &Klds[BSEL][issue * 512 + l * 8]);                     \
      } else {                                                                \
        int vj = issue - 16;                                                  \
        int dv = vj * 8 + (l >> 3);                                           \
        int c = l & 7;                                                        \
        const short* src = Vtp + (size_t)(b * 256 + dv) * SLEN + kt_ +        \
                           ((c ^ (dv & 7)) * 8);                              \
        gld_lds16(src, &Vlds[BSEL][vj * 512 + l * 8]);                        \
      }                                                                       \
    }                                                                         \
  }

  STAGE(0, 0);
  for (int t = 0; t < 8; ++t) {
    __syncthreads();               // drains stage(t) vmcnt; prev compute done
    if (t < 7) STAGE(t + 1, (t + 1) & 1);
    const int bsel = t & 1;
    const int kb = b * SLEN + kbase + t * 64;
    // QK^T (swapped: A=K from LDS, B=Q regs) -> s[e]: q=lc, k=e*16+lg*4+r
    f32x4 s[4] = {};
#pragma unroll
    for (int e = 0; e < 4; ++e)
#pragma unroll
      for (int kf = 0; kf < 4; ++kf) {
        bf16x8 kv = *(const bf16x8*)&Klds[bsel][(e * 16 + lc) * 128 +
                                               (((kf * 4 + lg) ^ (lc & 7)) * 8)];
        s[e] = mfma16(kv, qf[kf], s[e]);
      }
    // transform
    float wv[4][4];
#pragma unroll
    for (int e = 0; e < 4; ++e) {
      f32x4 k2v = *(const f32x4*)&k2a[kb + e * 16 + lg * 4];
#pragma unroll
      for (int r = 0; r < 4; ++r) {
        float d2 = q2s + k2v[r] - 2.0f * s[e][r];
        float g = __builtin_amdgcn_rcpf(fmaxf(d2, 1e-16f));
        wv[e][r] = g;
        den += g;
      }
    }
    // PV: P in-register as A-frag (slot perm matches Vtp layout)
#pragma unroll
    for (int ksub = 0; ksub < 2; ++ksub) {
      bf16x8 pa;
#pragma unroll
      for (int r = 0; r < 4; ++r) {
        pa[r] = f2bf(wv[2 * ksub][r]);
        pa[4 + r] = f2bf(wv[2 * ksub + 1][r]);
      }
#pragma unroll
      for (int nv = 0; nv < 16; ++nv) {
        int dv = nv * 16 + lc;
        bf16x8 bv = *(const bf16x8*)&Vlds[bsel][dv * 64 +
                                               (((ksub * 4 + lg) ^ (dv & 7)) * 8)];
        acc[nv] = mfma16(pa, bv, acc[nv]);
      }
    }
  }
#undef STAGE
  // den: reduce across lg groups (k-slices); lanes 0-15 hold den[q=lc]
  den += __shfl_xor(den, 16, 64);
  den += __shfl_xor(den, 32, 64);
  const int qt32 = qt * 4 + (w >> 1);
  const int pb = ((b * 64 + qt32) << 2) | ks;
  if (l < 16) denp[pb * 32 + (w & 1) * 16 + lc] = den;
  // nump partial (f32-accumulated over the full 512k window, one bf16 round)
  const size_t pbase = (size_t)pb * 32 * 256;
#pragma unroll
  for (int nv = 0; nv < 16; ++nv) {
    int dv = nv * 16 + lc;
#pragma unroll
    for (int r = 0; r < 4; ++r) {
      int rit = (w & 1) * 16 + lg * 4 + r;
      nump[pbase + (size_t)rit * 256 + dv] = f2bf(acc[nv][r]);
    }
  }
}

// ---------------------------------------------------------------- red -------
// AG[row][dv] = (sum_ks nump) / (sum_ks denp) * G[row][dv]
__global__ __launch_bounds__(256) void k_red(
    const short* __restrict__ nump, const float* __restrict__ denp,
    const short* __restrict__ O, short* __restrict__ AG) {
  int flat = blockIdx.x * 256 + threadIdx.x;   // 0..262143
  int idx8 = flat * 8;
  int row = idx8 >> 8;
  int dv0 = idx8 & 255;
  int b = row >> 11, srow = row & 2047;
  int qt = srow >> 5, rit = srow & 31;
  int blkbase = (b * 64 + qt) << 2;
  float num[8] = {};
  float den = 0.f;
#pragma unroll
  for (int ksi = 0; ksi < 4; ++ksi) {
    const size_t base = ((size_t)(blkbase + ksi) * 32 + rit) * 256 + dv0;
    bf16x8 v = *(const bf16x8*)&nump[base];
#pragma unroll
    for (int j = 0; j < 8; ++j) num[j] += bf2f(v[j]);
    den += denp[(blkbase + ksi) * 32 + rit];
  }
  float rden = 1.f / den;
  bf16x8 gv = *(const bf16x8*)&O[(size_t)row * 768 + 512 + dv0];
  bf16x8 o;
#pragma unroll
  for (int j = 0; j < 8; ++j) o[j] = f2bf(num[j] * rden * bf2f(gv[j]));
  *(bf16x8*)&AG[idx8] = o;
}

// ---------------------------------------------------------------- gemm3 -----
__global__ __launch_bounds__(256) void k_gemm3(
    const short* __restrict__ AG, const short* __restrict__ WpT,
    const float* __restrict__ X, const float* __restrict__ bp,
    float* __restrict__ Y) {
  __shared__ short At[128 * 32];
  __shared__ short Bt[128 * 32];
  const int tid = threadIdx.x;
  const int w = tid >> 6, l = tid & 63, lg = l >> 4, lc = l & 15;
  const int m0 = blockIdx.x * 128, n0 = blockIdx.y * 128;
  const int sr0 = w * 32 + (l >> 2);
  const int scc = (l & 3) * 8;
  const int wm = (w >> 1) * 64, wn = (w & 1) * 64;

  f32x4 acc[4][4] = {};
  const short* Ab = AG + (size_t)m0 * 256;
  const short* Bb = WpT + (size_t)n0 * 256;

  for (int kb = 0; kb < 256; kb += 32) {
    gld_lds16(Ab + (size_t)sr0 * 256 + kb + scc, &At[(w * 32) * 32]);
    gld_lds16(Ab + (size_t)(sr0 + 16) * 256 + kb + scc, &At[(w * 32 + 16) * 32]);
    gld_lds16(Bb + (size_t)sr0 * 256 + kb + scc, &Bt[(w * 32) * 32]);
    gld_lds16(Bb + (size_t)(sr0 + 16) * 256 + kb + scc, &Bt[(w * 32 + 16) * 32]);
    __syncthreads();
    bf16x8 af[4], bf[4];
#pragma unroll
    for (int mi = 0; mi < 4; ++mi)
      af[mi] = *(const bf16x8*)&At[(wm + mi * 16 + lc) * 32 + lg * 8];
#pragma unroll
    for (int ni = 0; ni < 4; ++ni)
      bf[ni] = *(const bf16x8*)&Bt[(wn + ni * 16 + lc) * 32 + lg * 8];
#pragma unroll
    for (int mi = 0; mi < 4; ++mi)
#pragma unroll
      for (int ni = 0; ni < 4; ++ni)
        acc[mi][ni] = mfma16(af[mi], bf[ni], acc[mi][ni]);
    __syncthreads();
  }
#pragma unroll
  for (int mi = 0; mi < 4; ++mi) {
    int gr = m0 + wm + mi * 16 + lg * 4;
#pragma unroll
    for (int ni = 0; ni < 4; ++ni) {
      int gc = n0 + wn + ni * 16 + lc;
      float bias = bp[gc];
#pragma unroll
      for (int r = 0; r < 4; ++r) {
        size_t idx = (size_t)(gr + r) * 1024 + gc;
        Y[idx] = acc[mi][ni][r] + X[idx] + bias;
      }
    }
  }
}

// ---------------------------------------------------------------- launch ----
extern "C" void kernel_launch(void* const* d_in, const int* in_sizes, int n_in,
                              void* d_out, int out_size, void* d_ws, size_t ws_size,
                              hipStream_t stream) {
  const float* X  = (const float*)d_in[0];
  const float* Wq = (const float*)d_in[1];
  const float* bq = (const float*)d_in[2];
  const float* Wk = (const float*)d_in[3];
  const float* bk = (const float*)d_in[4];
  const float* Wv = (const float*)d_in[5];
  const float* bv = (const float*)d_in[6];
  const float* Wg = (const float*)d_in[7];
  const float* bg = (const float*)d_in[8];
  const float* Wp = (const float*)d_in[9];
  const float* bp = (const float*)d_in[10];

  char* ws = (char*)d_ws;
  short* Xb    = (short*)(ws + 0);          // 16,777,216 B
  short* WcatT = (short*)(ws + 16777216);   //  1,572,864 B
  short* WpT   = (short*)(ws + 18350080);   //    524,288 B
  float* bcat  = (float*)(ws + 18874368);   //      3,072 B (pad to 4096)
  short* O     = (short*)(ws + 18878464);   // 12,582,912 B  (QKVG bf16)
  short* Vtp   = (short*)(ws + 31461376);   //  4,194,304 B
  float* q2a   = (float*)(ws + 35655680);   //     32,768 B
  float* k2a   = (float*)(ws + 35688448);   //     32,768 B
  short* AG    = (short*)(ws + 35721216);   //  4,194,304 B  (total ~39.9 MB)
  // Aliases: dead after k_gemm1, reused by split-K attention partials.
  short* nump  = (short*)(ws + 0);          // 16,777,216 B over Xb
  float* denp  = (float*)(ws + 16777216);   //    131,072 B over WcatT
  float* Y = (float*)d_out;

  hipLaunchKernelGGL(k_prep, dim3(4353), dim3(256), 0, stream,
                     X, Wq, bq, Wk, bk, Wv, bv, Wg, bg, Wp, Xb, WcatT, WpT, bcat);
  hipLaunchKernelGGL(k_gemm1, dim3(64, 6), dim3(256), 0, stream, Xb, WcatT, bcat, O, q2a, k2a);
  hipLaunchKernelGGL(k_vt, dim3(1024), dim3(256), 0, stream, O, Vtp);
  hipLaunchKernelGGL(k_attn, dim3(256), dim3(512), 0, stream, O, Vtp, q2a, k2a, nump, denp);
  hipLaunchKernelGGL(k_red, dim3(1024), dim3(256), 0, stream, nump, denp, O, AG);
  hipLaunchKernelGGL(k_gemm3, dim3(64, 8), dim3(256), 0, stream, AG, WpT, X, bp, Y);
}